// Round 1
// baseline (89.148 us; speedup 1.0000x reference)
//
#include <hip/hip_runtime.h>

#define NBOXES 4096
#define MAX_BS 128
#define INV4PI 0.07957747154594767f

// One block per pair (u,q). 128 threads: thread i owns target row i.
// Source box staged in LDS as float4 (x,y,z, INV4PI*qv masked).
// Inner loop trip count = bs_q; rows >= bs_u exit early.
// Scatter-add via global atomics (pairs share u boxes).
__global__ __launch_bounds__(128) void fmm_pair_kernel(
    const float* __restrict__ q_vec,    // [NBOXES][MAX_BS]
    const float* __restrict__ XX,       // [NBOXES][MAX_BS][3]
    const int*   __restrict__ bs_list,  // [NBOXES]
    const int2*  __restrict__ uq_boxes, // [NPAIRS]
    float*       __restrict__ out)      // [NBOXES][MAX_BS]
{
    const int p = blockIdx.x;
    const int t = threadIdx.x;          // 0..127

    const int2 uq = uq_boxes[p];
    const int u = uq.x;
    const int q = uq.y;
    const int bs_u = bs_list[u];
    const int bs_q = bs_list[q];

    __shared__ float4 sq[MAX_BS];

    // Stage source point t of box q: coords + masked, pre-scaled weight.
    {
        const float* Xq = XX + (size_t)q * (MAX_BS * 3);
        float x = Xq[3 * t + 0];
        float y = Xq[3 * t + 1];
        float z = Xq[3 * t + 2];
        float w = (t < bs_q) ? q_vec[(size_t)q * MAX_BS + t] * INV4PI : 0.0f;
        sq[t] = make_float4(x, y, z, w);
    }

    // Own target point (row i = t) of box u.
    const float* Xu = XX + (size_t)u * (MAX_BS * 3);
    const float xu = Xu[3 * t + 0];
    const float yu = Xu[3 * t + 1];
    const float zu = Xu[3 * t + 2];

    __syncthreads();

    if (t >= bs_u) return;   // row mask: dead rows (often a whole wave) exit

    float acc = 0.0f;
    const int n = bs_q;
#pragma unroll 4
    for (int j = 0; j < n; ++j) {
        const float4 s = sq[j];          // wave-uniform addr -> LDS broadcast
        const float dx = xu - s.x;
        const float dy = yu - s.y;
        const float dz = zu - s.z;
        const float r2 = dx * dx + dy * dy + dz * dz;
        float rinv = __builtin_amdgcn_rsqf(r2);
        rinv = (r2 > 0.0f) ? rinv : 0.0f;   // self-interaction -> 0
        acc = fmaf(s.w, rinv, acc);
    }

    atomicAdd(out + (size_t)u * MAX_BS + t, acc);
}

extern "C" void kernel_launch(void* const* d_in, const int* in_sizes, int n_in,
                              void* d_out, int out_size, void* d_ws, size_t ws_size,
                              hipStream_t stream) {
    const float* q_vec    = (const float*)d_in[0];
    const float* XX_list  = (const float*)d_in[1];
    const int*   bs_list  = (const int*)d_in[2];
    const int2*  uq_boxes = (const int2*)d_in[3];
    float* out = (float*)d_out;

    const int npairs = in_sizes[3] / 2;

    // Harness poisons d_out with 0xAA before every timed launch; we
    // accumulate with atomics, so zero it first (capture-safe memset node).
    hipMemsetAsync(d_out, 0, (size_t)out_size * sizeof(float), stream);

    fmm_pair_kernel<<<npairs, 128, 0, stream>>>(q_vec, XX_list, bs_list,
                                                uq_boxes, out);
}